// Round 2
// baseline (767.931 us; speedup 1.0000x reference)
//
#include <hip/hip_runtime.h>
#include <hip/hip_bf16.h>
#include <cstdint>
#include <cstddef>

// ---------------- types / helpers ----------------
typedef __bf16 bf16x8 __attribute__((ext_vector_type(8)));
typedef __bf16 bf16x4 __attribute__((ext_vector_type(4)));
typedef float  floatx4 __attribute__((ext_vector_type(4)));

#define DEV __device__ __forceinline__

DEV __bf16 f2b(float x) { return (__bf16)x; }

// async global->LDS, 16B per lane. LDS dest semantics: wave-uniform base + lane*16.
DEV void async_ld16(const void* g, void* l) {
    __builtin_amdgcn_global_load_lds(
        (const __attribute__((address_space(1))) unsigned int*)g,
        (__attribute__((address_space(3))) unsigned int*)l,
        16, 0, 0);
}

// ---------------- constants ----------------
#define BATCH 4096
#define DDIM  4624          // 68*68
#define DPAD  4640          // K padded to mult of 32
#define LDIM  68
#define EDIM  1024
#define N1    2048          // fc11|fc12 fused
#define KB    2048          // stage-B K (h11|h12)
#define N2PAD 4736          // 37*128

// ======================================================================
// fp32 -> bf16 convert with zero padding.
// dst[rows_total][DPAD]; valid region = src[rows_valid][K] (K divisible by 4).
// ======================================================================
__global__ void cvt_pad(const float* __restrict__ src, int rows_valid, int K,
                        __bf16* __restrict__ dst, int rows_total) {
    const int gpr = DPAD / 4;  // 1160 groups of 4 per row
    const long total = (long)rows_total * gpr;
    for (long g = blockIdx.x * (long)blockDim.x + threadIdx.x; g < total;
         g += gridDim.x * (long)blockDim.x) {
        int row = (int)(g / gpr);
        int c4  = (int)(g - (long)row * gpr) * 4;
        bf16x4 v;
        if (row < rows_valid && c4 < K) {
            floatx4 f = *(const floatx4*)(src + (size_t)row * K + c4);
            v[0] = f2b(f[0]); v[1] = f2b(f[1]); v[2] = f2b(f[2]); v[3] = f2b(f[3]);
        } else {
            v[0] = v[1] = v[2] = v[3] = (__bf16)0.0f;
        }
        *(bf16x4*)(dst + (size_t)row * DPAD + c4) = v;
    }
}

// w2_pad [144][2048] bf16: rows 0..67 = fc21 in cols 0..1023; rows 68..135 = fc22 in
// cols 1024..2047; everything else 0. (matches hbuf layout h11|h12)
__global__ void pad_w2(const float* __restrict__ w21, const float* __restrict__ w22,
                       __bf16* __restrict__ dst) {
    const int total = 144 * 512;  // groups of 4
    for (int g = blockIdx.x * blockDim.x + threadIdx.x; g < total;
         g += gridDim.x * blockDim.x) {
        int row = g >> 9;
        int c4  = (g & 511) * 4;
        bf16x4 v;
        v[0] = v[1] = v[2] = v[3] = (__bf16)0.0f;
        if (row < 68 && c4 < 1024) {
            floatx4 f = *(const floatx4*)(w21 + (size_t)row * EDIM + c4);
            v[0] = f2b(f[0]); v[1] = f2b(f[1]); v[2] = f2b(f[2]); v[3] = f2b(f[3]);
        } else if (row >= 68 && row < 136 && c4 >= 1024) {
            floatx4 f = *(const floatx4*)(w22 + (size_t)(row - 68) * EDIM + (c4 - 1024));
            v[0] = f2b(f[0]); v[1] = f2b(f[1]); v[2] = f2b(f[2]); v[3] = f2b(f[3]);
        }
        *(bf16x4*)(dst + (size_t)row * KB + c4) = v;
    }
}

// ======================================================================
// main MFMA GEMM (m97 structure): C[M,N] = epi(A[M,K] * W[N,K]^T + bias)
// Both A and W are pre-padded to lda/ldb = DPAD-style zero-padded buffers: NO clamps.
// 128x128 tile, BK=32, 256 thr = 4 waves, each wave 64x64 (4x4 frags of 16x16x32)
// EPI 0: relu(acc + (col<1024 ? b0[col] : b1[col-1024])) -> bf16 outb
// EPI 1: sigmoid(acc + b0[col]) -> fp32 outf, only col < DDIM
// ======================================================================
template <int EPI>
__launch_bounds__(256, 2)
__global__ void gemm_bt(const __bf16* __restrict__ A, int lda,
                        const __bf16* __restrict__ W, int ldb, int KT,
                        __bf16* __restrict__ outb, float* __restrict__ outf, int ldc,
                        const float* __restrict__ bias0, const float* __restrict__ bias1) {
    __shared__ __align__(16) __bf16 smA[128 * 32];
    __shared__ __align__(16) __bf16 smB[128 * 32];

    const int t  = threadIdx.x;
    const int l  = t & 63;
    const int w  = t >> 6;
    const int m0 = blockIdx.x * 128;
    const int n0 = blockIdx.y * 128;
    const int wm = (w & 1) * 64;
    const int wn = (w >> 1) * 64;

    // staging: thread t loads 16B; row = t/4 (+64 for 2nd inst), col-group = t%4
    const int srow = t >> 2;
    const int scol = (t & 3) * 8;
    const __bf16* pa0 = A + (size_t)(m0 + srow) * lda + scol;
    const __bf16* pa1 = A + (size_t)(m0 + srow + 64) * lda + scol;
    const __bf16* pb0 = W + (size_t)(n0 + srow) * ldb + scol;
    const __bf16* pb1 = W + (size_t)(n0 + srow + 64) * ldb + scol;
    char* dA = (char*)smA + t * 16;
    char* dB = (char*)smB + t * 16;

    floatx4 acc[4][4];
#pragma unroll
    for (int mi = 0; mi < 4; ++mi)
#pragma unroll
        for (int ni = 0; ni < 4; ++ni) {
            floatx4 z = {0.f, 0.f, 0.f, 0.f};
            acc[mi][ni] = z;
        }

    for (int kt = 0; kt < KT; ++kt) {
        async_ld16(pa0, dA);
        async_ld16(pa1, dA + 4096);
        async_ld16(pb0, dB);
        async_ld16(pb1, dB + 4096);
        pa0 += 32; pa1 += 32; pb0 += 32; pb1 += 32;
        __syncthreads();   // drains vmcnt then barrier

        bf16x8 af[4], bfr[4];
#pragma unroll
        for (int mi = 0; mi < 4; ++mi) {
            int r = wm + mi * 16 + (l & 15);
            af[mi] = *(const bf16x8*)((const char*)smA + r * 64 + (l >> 4) * 16);
        }
#pragma unroll
        for (int ni = 0; ni < 4; ++ni) {
            int r = wn + ni * 16 + (l & 15);
            bfr[ni] = *(const bf16x8*)((const char*)smB + r * 64 + (l >> 4) * 16);
        }
#pragma unroll
        for (int mi = 0; mi < 4; ++mi)
#pragma unroll
            for (int ni = 0; ni < 4; ++ni)
                acc[mi][ni] = __builtin_amdgcn_mfma_f32_16x16x32_bf16(af[mi], bfr[ni],
                                                                     acc[mi][ni], 0, 0, 0);
        __syncthreads();   // protect LDS before next stage
    }

    // epilogue: C/D layout col = lane&15, row = (lane>>4)*4 + reg  [m89/m91]
    const int colbase = n0 + wn + (l & 15);
    const int rowbase = m0 + wm + (l >> 4) * 4;
#pragma unroll
    for (int ni = 0; ni < 4; ++ni) {
        int col = colbase + ni * 16;
        if (EPI == 1 && col >= DDIM) continue;
        float bias = (EPI == 0)
                         ? ((col < 1024) ? bias0[col] : bias1[col - 1024])
                         : bias0[col];
#pragma unroll
        for (int mi = 0; mi < 4; ++mi) {
            int row = rowbase + mi * 16;
#pragma unroll
            for (int r = 0; r < 4; ++r) {
                float v = acc[mi][ni][r] + bias;
                if (EPI == 0) {
                    v = v > 0.f ? v : 0.f;
                    outb[(size_t)(row + r) * ldc + col] = f2b(v);
                } else {
                    v = 1.f / (1.f + __expf(-v));
                    outf[(size_t)(row + r) * ldc + col] = v;
                }
            }
        }
    }
}

// ======================================================================
// stage B: muvar[4096][136] += h[4096][2048] * w2_pad[144][2048]^T  (K-split x4, fp32 atomics)
// 1 wave per block: 16 rows x 144 cols (9 n-frags), direct global loads (w2 is L2-hot)
// ======================================================================
__launch_bounds__(64, 4)
__global__ void gemmB(const __bf16* __restrict__ h, const __bf16* __restrict__ w2,
                      float* __restrict__ muvar) {
    const int l    = threadIdx.x;
    const int m0   = blockIdx.x * 16;
    const int k0   = blockIdx.y * 512;
    const int row  = l & 15;
    const int quad = l >> 4;

    floatx4 acc[9];
#pragma unroll
    for (int ni = 0; ni < 9; ++ni) {
        floatx4 z = {0.f, 0.f, 0.f, 0.f};
        acc[ni] = z;
    }

    const __bf16* ap = h + (size_t)(m0 + row) * KB + k0 + quad * 8;
    for (int kt = 0; kt < 16; ++kt) {
        bf16x8 a = *(const bf16x8*)ap;
        ap += 32;
#pragma unroll
        for (int ni = 0; ni < 9; ++ni) {
            const __bf16* bp = w2 + (size_t)(ni * 16 + row) * KB + k0 + kt * 32 + quad * 8;
            bf16x8 b = *(const bf16x8*)bp;
            acc[ni] = __builtin_amdgcn_mfma_f32_16x16x32_bf16(a, b, acc[ni], 0, 0, 0);
        }
    }
#pragma unroll
    for (int ni = 0; ni < 9; ++ni) {
        int col = ni * 16 + row;
        if (col < 136) {
#pragma unroll
            for (int r = 0; r < 4; ++r) {
                int orow = m0 + quad * 4 + r;
                atomicAdd(&muvar[(size_t)orow * 136 + col], acc[ni][r]);
            }
        }
    }
}

// ======================================================================
// decode (all fp32): mu/logvar(+bias) -> z -> h3_0 -> h4_0 -> h51 -> outer -> A2 (bf16, padded)
// also writes mu, logvar, y to d_out. Branches 1..4 are dead code (recon uses h51 only).
// 16 rows per 256-thread block.
// ======================================================================
__global__ void decode(const float* __restrict__ muvar, const float* __restrict__ eps,
                       const float* __restrict__ b21, const float* __restrict__ b22,
                       const float* __restrict__ W3, const float* __restrict__ b3,
                       const float* __restrict__ W4, const float* __restrict__ b4,
                       const float* __restrict__ W5, const float* __restrict__ b5,
                       const float* __restrict__ fcyw, const float* __restrict__ fcyb,
                       float* __restrict__ out_mu, float* __restrict__ out_lv,
                       float* __restrict__ out_y, __bf16* __restrict__ A2) {
    __shared__ float w3s[DDIM], w4s[DDIM], w5s[DDIM];
    __shared__ float b3s[LDIM], b4s[LDIM], b5s[LDIM], fys[LDIM];
    __shared__ float zb[16][LDIM], h3b[16][LDIM], h51b[16][LDIM];

    const int t  = threadIdx.x;
    const int r0 = blockIdx.x * 16;

    for (int i = t; i < DDIM; i += 256) {  // branch 0 = first 68*68 of each tensor
        w3s[i] = W3[i];
        w4s[i] = W4[i];
        w5s[i] = W5[i];
    }
    if (t < LDIM) {
        b3s[t] = b3[t];
        b4s[t] = b4[t];
        b5s[t] = b5[t];
        fys[t] = fcyw[t];
    }
    __syncthreads();

    // z = mu + eps*exp(0.5*logvar); store mu/logvar fp32
    for (int idx = t; idx < 16 * LDIM; idx += 256) {
        int r = idx / LDIM, o = idx - r * LDIM;
        int row = r0 + r;
        float mu = muvar[(size_t)row * 136 + o] + b21[o];
        float lv = muvar[(size_t)row * 136 + 68 + o] + b22[o];
        float z  = mu + eps[(size_t)row * LDIM + o] * __expf(0.5f * lv);
        zb[r][o] = z;
        out_mu[(size_t)row * LDIM + o] = mu;
        out_lv[(size_t)row * LDIM + o] = lv;
    }
    if (t < 16) {  // y = mu @ fcy_w^T + fcy_b
        int row = r0 + t;
        float s = fcyb[0];
        for (int o = 0; o < LDIM; ++o)
            s += (muvar[(size_t)row * 136 + o] + b21[o]) * fys[o];
        out_y[row] = s;
    }
    __syncthreads();

    // h3_0 = z @ W3_0^T + b3_0   (branch 0: NO sigmoid)
    for (int idx = t; idx < 16 * LDIM; idx += 256) {
        int r = idx / LDIM, o = idx - r * LDIM;
        float s = b3s[o];
        for (int d = 0; d < LDIM; ++d) s += zb[r][d] * w3s[o * LDIM + d];
        h3b[r][o] = s;
    }
    __syncthreads();

    // h4_0 = sigmoid(h3_0 @ W4_0^T + b4_0)  -> reuse zb
    for (int idx = t; idx < 16 * LDIM; idx += 256) {
        int r = idx / LDIM, o = idx - r * LDIM;
        float s = b4s[o];
        for (int d = 0; d < LDIM; ++d) s += h3b[r][d] * w4s[o * LDIM + d];
        zb[r][o] = 1.f / (1.f + __expf(-s));
    }
    __syncthreads();

    // h51 = h4_0 @ W5_0^T + b5_0
    for (int idx = t; idx < 16 * LDIM; idx += 256) {
        int r = idx / LDIM, o = idx - r * LDIM;
        float s = b5s[o];
        for (int d = 0; d < LDIM; ++d) s += zb[r][d] * w5s[o * LDIM + d];
        h51b[r][o] = s;
    }
    __syncthreads();

    // outer product, K-padded with zeros: A2[row][i*68+j] = h51[i]*h51[j], bf16
    for (int idx = t; idx < 16 * (DPAD / 4); idx += 256) {
        int r  = idx / (DPAD / 4);
        int c4 = (idx - r * (DPAD / 4)) * 4;
        int row = r0 + r;
        bf16x4 v;
#pragma unroll
        for (int u = 0; u < 4; ++u) {
            int c = c4 + u;
            float val = 0.f;
            if (c < DDIM) {
                int i = c / LDIM;
                int j = c - i * LDIM;
                val = h51b[r][i] * h51b[r][j];
            }
            v[u] = f2b(val);
        }
        *(bf16x4*)(A2 + (size_t)row * DPAD + c4) = v;
    }
}

// ======================================================================
extern "C" void kernel_launch(void* const* d_in, const int* in_sizes, int n_in,
                              void* d_out, int out_size, void* d_ws, size_t ws_size,
                              hipStream_t stream) {
    const float* x    = (const float*)d_in[0];
    const float* eps  = (const float*)d_in[1];
    const float* w11  = (const float*)d_in[2];
    const float* b11  = (const float*)d_in[3];
    const float* w12  = (const float*)d_in[4];
    const float* b12  = (const float*)d_in[5];
    const float* w21  = (const float*)d_in[6];
    const float* b21  = (const float*)d_in[7];
    const float* w22  = (const float*)d_in[8];
    const float* b22  = (const float*)d_in[9];
    const float* W3   = (const float*)d_in[10];
    const float* b3   = (const float*)d_in[11];
    const float* W4   = (const float*)d_in[12];
    const float* b4   = (const float*)d_in[13];
    const float* W5   = (const float*)d_in[14];
    const float* b5   = (const float*)d_in[15];
    const float* w6   = (const float*)d_in[16];
    const float* b6   = (const float*)d_in[17];
    const float* fcyw = (const float*)d_in[18];
    const float* fcyb = (const float*)d_in[19];

    float* out       = (float*)d_out;
    float* out_recon = out;
    float* out_mu    = out + (size_t)BATCH * DDIM;
    float* out_lv    = out_mu + (size_t)BATCH * LDIM;
    float* out_y     = out_lv + (size_t)BATCH * LDIM;

    // ws layout (bytes, 256B-aligned)
    char* ws = (char*)d_ws;
    size_t off = 0;
    __bf16* xb     = (__bf16*)(ws + off); off += (size_t)BATCH * DPAD * 2;   // 38,010,880
    __bf16* w1_pad = (__bf16*)(ws + off); off += (size_t)N1 * DPAD * 2;      // 19,005,440
    __bf16* w6pad  = (__bf16*)(ws + off); off += (size_t)N2PAD * DPAD * 2;   // 43,950,080
    __bf16* hbuf   = (__bf16*)(ws + off); off += (size_t)BATCH * KB * 2;     // 16,777,216
    __bf16* w2_pad = (__bf16*)(ws + off); off += (size_t)144 * KB * 2;       //    589,824
    float*  muvar  = (float*) (ws + off); off += (size_t)BATCH * 136 * 4;    //  2,228,224
    __bf16* A2     = (__bf16*)(ws + off);                                    // 38,010,880
    // total ~151.2 MB

    hipMemsetAsync(muvar, 0, (size_t)BATCH * 136 * 4, stream);

    // fp32 -> zero-padded bf16 staging buffers
    cvt_pad<<<2048, 256, 0, stream>>>(x, BATCH, DDIM, xb, BATCH);
    cvt_pad<<<512, 256, 0, stream>>>(w11, 1024, DDIM, w1_pad, 1024);
    cvt_pad<<<512, 256, 0, stream>>>(w12, 1024, DDIM, w1_pad + (size_t)1024 * DPAD, 1024);
    cvt_pad<<<2048, 256, 0, stream>>>(w6, DDIM, DDIM, w6pad, N2PAD);
    pad_w2<<<72, 256, 0, stream>>>(w21, w22, w2_pad);

    // GEMM1: h = relu(x @ [fc11|fc12]^T + b)   M=4096 N=2048 K=4640
    gemm_bt<0><<<dim3(32, 16), 256, 0, stream>>>(
        xb, DPAD, w1_pad, DPAD, DPAD / 32, hbuf, nullptr, N1, b11, b12);

    // stage B: muvar = h @ w2_pad^T (K-split, atomics)
    gemmB<<<dim3(BATCH / 16, 4), 64, 0, stream>>>(hbuf, w2_pad, muvar);

    // decode + outer product -> A2 (bf16, zero-padded)
    decode<<<BATCH / 16, 256, 0, stream>>>(muvar, eps, b21, b22, W3, b3, W4, b4, W5, b5,
                                           fcyw, fcyb, out_mu, out_lv, out_y, A2);

    // GEMM2: recon = sigmoid(A2 @ fc6^T + b6)  M=4096 N=4736(valid 4624) K=4640, fp32 out
    gemm_bt<1><<<dim3(32, N2PAD / 128), 256, 0, stream>>>(
        A2, DPAD, w6pad, DPAD, DPAD / 32, nullptr, out_recon, DDIM, b6, nullptr);
}

// Round 3
// 594.228 us; speedup vs baseline: 1.2923x; 1.2923x over previous
//
#include <hip/hip_runtime.h>
#include <hip/hip_bf16.h>
#include <cstdint>
#include <cstddef>

// ---------------- types / helpers ----------------
typedef __bf16 bf16x8 __attribute__((ext_vector_type(8)));
typedef __bf16 bf16x4 __attribute__((ext_vector_type(4)));
typedef float  floatx4 __attribute__((ext_vector_type(4)));

#define DEV __device__ __forceinline__

DEV __bf16 f2b(float x) { return (__bf16)x; }

// async global->LDS, 16B per lane. LDS dest semantics: wave-uniform base + lane*16.
DEV void async_ld16(const void* g, void* l) {
    __builtin_amdgcn_global_load_lds(
        (const __attribute__((address_space(1))) unsigned int*)g,
        (__attribute__((address_space(3))) unsigned int*)l,
        16, 0, 0);
}

// ---------------- constants ----------------
#define BATCH 4096
#define DDIM  4624          // 68*68
#define DPAD  4640          // GEMM1 K padded to mult of 32
#define LDIM  68
#define EDIM  1024
#define N1    2048          // fc11|fc12 fused
#define KB    2048          // stage-B K (h11|h12)
#define N2PAD 4736          // 37*128
#define NPAIR 2346          // 68*69/2 symmetric pairs
#define K2PAD 2368          // NPAIR padded to mult of 32 (74*32)

// ======================================================================
// fp32 -> bf16 convert with zero padding. dst[rows_total][DPAD].
// ======================================================================
__global__ void cvt_pad(const float* __restrict__ src, int rows_valid, int K,
                        __bf16* __restrict__ dst, int rows_total) {
    const int gpr = DPAD / 4;
    const long total = (long)rows_total * gpr;
    for (long g = blockIdx.x * (long)blockDim.x + threadIdx.x; g < total;
         g += gridDim.x * (long)blockDim.x) {
        int row = (int)(g / gpr);
        int c4  = (int)(g - (long)row * gpr) * 4;
        bf16x4 v;
        if (row < rows_valid && c4 < K) {
            floatx4 f = *(const floatx4*)(src + (size_t)row * K + c4);
            v[0] = f2b(f[0]); v[1] = f2b(f[1]); v[2] = f2b(f[2]); v[3] = f2b(f[3]);
        } else {
            v[0] = v[1] = v[2] = v[3] = (__bf16)0.0f;
        }
        *(bf16x4*)(dst + (size_t)row * DPAD + c4) = v;
    }
}

// w2_pad [144][2048] bf16: rows 0..67 = fc21 in cols 0..1023; rows 68..135 = fc22 in
// cols 1024..2047; everything else 0. (matches hbuf layout h11|h12)
__global__ void pad_w2(const float* __restrict__ w21, const float* __restrict__ w22,
                       __bf16* __restrict__ dst) {
    const int total = 144 * 512;
    for (int g = blockIdx.x * blockDim.x + threadIdx.x; g < total;
         g += gridDim.x * blockDim.x) {
        int row = g >> 9;
        int c4  = (g & 511) * 4;
        bf16x4 v;
        v[0] = v[1] = v[2] = v[3] = (__bf16)0.0f;
        if (row < 68 && c4 < 1024) {
            floatx4 f = *(const floatx4*)(w21 + (size_t)row * EDIM + c4);
            v[0] = f2b(f[0]); v[1] = f2b(f[1]); v[2] = f2b(f[2]); v[3] = f2b(f[3]);
        } else if (row >= 68 && row < 136 && c4 >= 1024) {
            floatx4 f = *(const floatx4*)(w22 + (size_t)(row - 68) * EDIM + (c4 - 1024));
            v[0] = f2b(f[0]); v[1] = f2b(f[1]); v[2] = f2b(f[2]); v[3] = f2b(f[3]);
        }
        *(bf16x4*)(dst + (size_t)row * KB + c4) = v;
    }
}

// ======================================================================
// pair table: p -> (i,j), i<=j, p = i*(137-i)/2 + (j-i). Built in LDS.
// ======================================================================
DEV void build_ptab(unsigned short* ptab, int t, int nthr) {
    for (int i = t; i < LDIM; i += nthr) {
        int p0 = i * (137 - i) / 2;
        for (int j = i; j < LDIM; ++j)
            ptab[p0 + (j - i)] = (unsigned short)((i << 8) | j);
    }
}

// ======================================================================
// w6sym: one block per output row o. dst[o][p] = w6[o][i,j] + w6[o][j,i] (i<j),
// w6[o][i,i] (i==j); zero pad for p>=NPAIR and o>=DDIM.
// ======================================================================
__global__ void w6sym_build(const float* __restrict__ w6, __bf16* __restrict__ dst) {
    __shared__ float row[DDIM];
    __shared__ unsigned short ptab[K2PAD];
    const int o = blockIdx.x;
    const int t = threadIdx.x;
    if (o < DDIM) {
        const float* src = w6 + (size_t)o * DDIM;
        for (int idx = t; idx < DDIM / 4; idx += 256)
            *(floatx4*)(row + idx * 4) = *(const floatx4*)(src + idx * 4);
    }
    build_ptab(ptab, t, 256);
    __syncthreads();
    for (int p4 = t; p4 < K2PAD / 4; p4 += 256) {
        bf16x4 v;
#pragma unroll
        for (int u = 0; u < 4; ++u) {
            int p = p4 * 4 + u;
            float val = 0.f;
            if (o < DDIM && p < NPAIR) {
                int ij = ptab[p];
                int i = ij >> 8, j = ij & 255;
                val = (i == j) ? row[i * LDIM + i] : (row[i * LDIM + j] + row[j * LDIM + i]);
            }
            v[u] = f2b(val);
        }
        *(bf16x4*)(dst + (size_t)o * K2PAD + p4 * 4) = v;
    }
}

// ======================================================================
// main MFMA GEMM (m97 structure): C[M,N] = epi(A[M,K] * W[N,K]^T + bias)
// A and W pre-padded (zero pad): NO clamps. 128x128 tile, BK=32, 4 waves,
// each wave 64x64 via 4x4 frags of 16x16x32.
// EPI 0: relu(acc + (col<1024 ? b0[col] : b1[col-1024])) -> bf16 outb
// EPI 1: sigmoid(acc + b0[col]) -> fp32 outf, only col < DDIM
// ======================================================================
template <int EPI>
__launch_bounds__(256, 2)
__global__ void gemm_bt(const __bf16* __restrict__ A, int lda,
                        const __bf16* __restrict__ W, int ldb, int KT,
                        __bf16* __restrict__ outb, float* __restrict__ outf, int ldc,
                        const float* __restrict__ bias0, const float* __restrict__ bias1) {
    __shared__ __align__(16) __bf16 smA[128 * 32];
    __shared__ __align__(16) __bf16 smB[128 * 32];

    const int t  = threadIdx.x;
    const int l  = t & 63;
    const int w  = t >> 6;
    const int m0 = blockIdx.x * 128;
    const int n0 = blockIdx.y * 128;
    const int wm = (w & 1) * 64;
    const int wn = (w >> 1) * 64;

    const int srow = t >> 2;
    const int scol = (t & 3) * 8;
    const __bf16* pa0 = A + (size_t)(m0 + srow) * lda + scol;
    const __bf16* pa1 = A + (size_t)(m0 + srow + 64) * lda + scol;
    const __bf16* pb0 = W + (size_t)(n0 + srow) * ldb + scol;
    const __bf16* pb1 = W + (size_t)(n0 + srow + 64) * ldb + scol;
    char* dA = (char*)smA + t * 16;
    char* dB = (char*)smB + t * 16;

    floatx4 acc[4][4];
#pragma unroll
    for (int mi = 0; mi < 4; ++mi)
#pragma unroll
        for (int ni = 0; ni < 4; ++ni) {
            floatx4 z = {0.f, 0.f, 0.f, 0.f};
            acc[mi][ni] = z;
        }

    for (int kt = 0; kt < KT; ++kt) {
        async_ld16(pa0, dA);
        async_ld16(pa1, dA + 4096);
        async_ld16(pb0, dB);
        async_ld16(pb1, dB + 4096);
        pa0 += 32; pa1 += 32; pb0 += 32; pb1 += 32;
        __syncthreads();

        bf16x8 af[4], bfr[4];
#pragma unroll
        for (int mi = 0; mi < 4; ++mi) {
            int r = wm + mi * 16 + (l & 15);
            af[mi] = *(const bf16x8*)((const char*)smA + r * 64 + (l >> 4) * 16);
        }
#pragma unroll
        for (int ni = 0; ni < 4; ++ni) {
            int r = wn + ni * 16 + (l & 15);
            bfr[ni] = *(const bf16x8*)((const char*)smB + r * 64 + (l >> 4) * 16);
        }
#pragma unroll
        for (int mi = 0; mi < 4; ++mi)
#pragma unroll
            for (int ni = 0; ni < 4; ++ni)
                acc[mi][ni] = __builtin_amdgcn_mfma_f32_16x16x32_bf16(af[mi], bfr[ni],
                                                                     acc[mi][ni], 0, 0, 0);
        __syncthreads();
    }

    // epilogue: C/D layout col = lane&15, row = (lane>>4)*4 + reg  [m89/m91]
    const int colbase = n0 + wn + (l & 15);
    const int rowbase = m0 + wm + (l >> 4) * 4;
#pragma unroll
    for (int ni = 0; ni < 4; ++ni) {
        int col = colbase + ni * 16;
        if (EPI == 1 && col >= DDIM) continue;
        float bias = (EPI == 0)
                         ? ((col < 1024) ? bias0[col] : bias1[col - 1024])
                         : bias0[col];
#pragma unroll
        for (int mi = 0; mi < 4; ++mi) {
            int row = rowbase + mi * 16;
#pragma unroll
            for (int r = 0; r < 4; ++r) {
                float v = acc[mi][ni][r] + bias;
                if (EPI == 0) {
                    v = v > 0.f ? v : 0.f;
                    outb[(size_t)(row + r) * ldc + col] = f2b(v);
                } else {
                    v = 1.f / (1.f + __expf(-v));
                    outf[(size_t)(row + r) * ldc + col] = v;
                }
            }
        }
    }
}

// ======================================================================
// stage B: muvar[4096][136] += h[4096][2048] * w2_pad[144][2048]^T (K-split x4, atomics)
// ======================================================================
__launch_bounds__(64, 4)
__global__ void gemmB(const __bf16* __restrict__ h, const __bf16* __restrict__ w2,
                      float* __restrict__ muvar) {
    const int l    = threadIdx.x;
    const int m0   = blockIdx.x * 16;
    const int k0   = blockIdx.y * 512;
    const int row  = l & 15;
    const int quad = l >> 4;

    floatx4 acc[9];
#pragma unroll
    for (int ni = 0; ni < 9; ++ni) {
        floatx4 z = {0.f, 0.f, 0.f, 0.f};
        acc[ni] = z;
    }

    const __bf16* ap = h + (size_t)(m0 + row) * KB + k0 + quad * 8;
    for (int kt = 0; kt < 16; ++kt) {
        bf16x8 a = *(const bf16x8*)ap;
        ap += 32;
#pragma unroll
        for (int ni = 0; ni < 9; ++ni) {
            const __bf16* bp = w2 + (size_t)(ni * 16 + row) * KB + k0 + kt * 32 + quad * 8;
            bf16x8 b = *(const bf16x8*)bp;
            acc[ni] = __builtin_amdgcn_mfma_f32_16x16x32_bf16(a, b, acc[ni], 0, 0, 0);
        }
    }
#pragma unroll
    for (int ni = 0; ni < 9; ++ni) {
        int col = ni * 16 + row;
        if (col < 136) {
#pragma unroll
            for (int r = 0; r < 4; ++r) {
                int orow = m0 + quad * 4 + r;
                atomicAdd(&muvar[(size_t)orow * 136 + col], acc[ni][r]);
            }
        }
    }
}

// ======================================================================
// decode (fp32): mu/logvar(+bias) -> z -> h3_0 -> h4_0 -> h51 -> symmetric-pair A2
// also writes mu, logvar, y. Branches 1..4 dead (recon uses h51 only).
// ======================================================================
__global__ void decode(const float* __restrict__ muvar, const float* __restrict__ eps,
                       const float* __restrict__ b21, const float* __restrict__ b22,
                       const float* __restrict__ W3, const float* __restrict__ b3,
                       const float* __restrict__ W4, const float* __restrict__ b4,
                       const float* __restrict__ W5, const float* __restrict__ b5,
                       const float* __restrict__ fcyw, const float* __restrict__ fcyb,
                       float* __restrict__ out_mu, float* __restrict__ out_lv,
                       float* __restrict__ out_y, __bf16* __restrict__ A2) {
    __shared__ float w3s[DDIM], w4s[DDIM], w5s[DDIM];
    __shared__ float b3s[LDIM], b4s[LDIM], b5s[LDIM], fys[LDIM];
    __shared__ float zb[16][LDIM], h3b[16][LDIM], h51b[16][LDIM];
    __shared__ unsigned short ptab[K2PAD];

    const int t  = threadIdx.x;
    const int r0 = blockIdx.x * 16;

    for (int i = t; i < DDIM; i += 256) {  // branch 0 = first 68*68 of each tensor
        w3s[i] = W3[i];
        w4s[i] = W4[i];
        w5s[i] = W5[i];
    }
    if (t < LDIM) {
        b3s[t] = b3[t];
        b4s[t] = b4[t];
        b5s[t] = b5[t];
        fys[t] = fcyw[t];
    }
    build_ptab(ptab, t, 256);
    __syncthreads();

    for (int idx = t; idx < 16 * LDIM; idx += 256) {
        int r = idx / LDIM, o = idx - r * LDIM;
        int row = r0 + r;
        float mu = muvar[(size_t)row * 136 + o] + b21[o];
        float lv = muvar[(size_t)row * 136 + 68 + o] + b22[o];
        float z  = mu + eps[(size_t)row * LDIM + o] * __expf(0.5f * lv);
        zb[r][o] = z;
        out_mu[(size_t)row * LDIM + o] = mu;
        out_lv[(size_t)row * LDIM + o] = lv;
    }
    if (t < 16) {
        int row = r0 + t;
        float s = fcyb[0];
        for (int o = 0; o < LDIM; ++o)
            s += (muvar[(size_t)row * 136 + o] + b21[o]) * fys[o];
        out_y[row] = s;
    }
    __syncthreads();

    // h3_0 = z @ W3_0^T + b3_0   (branch 0: NO sigmoid)
    for (int idx = t; idx < 16 * LDIM; idx += 256) {
        int r = idx / LDIM, o = idx - r * LDIM;
        float s = b3s[o];
        for (int d = 0; d < LDIM; ++d) s += zb[r][d] * w3s[o * LDIM + d];
        h3b[r][o] = s;
    }
    __syncthreads();

    // h4_0 = sigmoid(h3_0 @ W4_0^T + b4_0)  -> reuse zb
    for (int idx = t; idx < 16 * LDIM; idx += 256) {
        int r = idx / LDIM, o = idx - r * LDIM;
        float s = b4s[o];
        for (int d = 0; d < LDIM; ++d) s += h3b[r][d] * w4s[o * LDIM + d];
        zb[r][o] = 1.f / (1.f + __expf(-s));
    }
    __syncthreads();

    // h51 = h4_0 @ W5_0^T + b5_0
    for (int idx = t; idx < 16 * LDIM; idx += 256) {
        int r = idx / LDIM, o = idx - r * LDIM;
        float s = b5s[o];
        for (int d = 0; d < LDIM; ++d) s += zb[r][d] * w5s[o * LDIM + d];
        h51b[r][o] = s;
    }
    __syncthreads();

    // symmetric-pair "outer product": A2[row][p] = h51[i]*h51[j] (factor 2 folded into w6sym)
    for (int idx = t; idx < 16 * (K2PAD / 4); idx += 256) {
        int r  = idx / (K2PAD / 4);
        int p4 = (idx - r * (K2PAD / 4)) * 4;
        int row = r0 + r;
        bf16x4 v;
#pragma unroll
        for (int u = 0; u < 4; ++u) {
            int p = p4 + u;
            float val = 0.f;
            if (p < NPAIR) {
                int ij = ptab[p];
                val = h51b[r][ij >> 8] * h51b[r][ij & 255];
            }
            v[u] = f2b(val);
        }
        *(bf16x4*)(A2 + (size_t)row * K2PAD + p4) = v;
    }
}

// ======================================================================
extern "C" void kernel_launch(void* const* d_in, const int* in_sizes, int n_in,
                              void* d_out, int out_size, void* d_ws, size_t ws_size,
                              hipStream_t stream) {
    const float* x    = (const float*)d_in[0];
    const float* eps  = (const float*)d_in[1];
    const float* w11  = (const float*)d_in[2];
    const float* b11  = (const float*)d_in[3];
    const float* w12  = (const float*)d_in[4];
    const float* b12  = (const float*)d_in[5];
    const float* w21  = (const float*)d_in[6];
    const float* b21  = (const float*)d_in[7];
    const float* w22  = (const float*)d_in[8];
    const float* b22  = (const float*)d_in[9];
    const float* W3   = (const float*)d_in[10];
    const float* b3   = (const float*)d_in[11];
    const float* W4   = (const float*)d_in[12];
    const float* b4   = (const float*)d_in[13];
    const float* W5   = (const float*)d_in[14];
    const float* b5   = (const float*)d_in[15];
    const float* w6   = (const float*)d_in[16];
    const float* b6   = (const float*)d_in[17];
    const float* fcyw = (const float*)d_in[18];
    const float* fcyb = (const float*)d_in[19];

    float* out       = (float*)d_out;
    float* out_recon = out;
    float* out_mu    = out + (size_t)BATCH * DDIM;
    float* out_lv    = out_mu + (size_t)BATCH * LDIM;
    float* out_y     = out_lv + (size_t)BATCH * LDIM;

    // ws layout (bytes, 256B-aligned)
    char* ws = (char*)d_ws;
    size_t off = 0;
    __bf16* xb     = (__bf16*)(ws + off); off += (size_t)BATCH * DPAD * 2;   // 38.0 MB
    __bf16* w1_pad = (__bf16*)(ws + off); off += (size_t)N1 * DPAD * 2;      // 19.0 MB
    __bf16* w6s    = (__bf16*)(ws + off); off += (size_t)N2PAD * K2PAD * 2;  // 22.4 MB
    __bf16* hbuf   = (__bf16*)(ws + off); off += (size_t)BATCH * KB * 2;     // 16.8 MB
    __bf16* w2_pad = (__bf16*)(ws + off); off += (size_t)144 * KB * 2;       //  0.6 MB
    float*  muvar  = (float*) (ws + off); off += (size_t)BATCH * 136 * 4;    //  2.2 MB
    __bf16* A2     = (__bf16*)(ws + off);                                    // 19.4 MB
    // total ~118 MB

    hipMemsetAsync(muvar, 0, (size_t)BATCH * 136 * 4, stream);

    // fp32 -> zero-padded bf16 staging buffers
    cvt_pad<<<2048, 256, 0, stream>>>(x, BATCH, DDIM, xb, BATCH);
    cvt_pad<<<512, 256, 0, stream>>>(w11, 1024, DDIM, w1_pad, 1024);
    cvt_pad<<<512, 256, 0, stream>>>(w12, 1024, DDIM, w1_pad + (size_t)1024 * DPAD, 1024);
    w6sym_build<<<N2PAD, 256, 0, stream>>>(w6, w6s);
    pad_w2<<<72, 256, 0, stream>>>(w21, w22, w2_pad);

    // GEMM1: h = relu(x @ [fc11|fc12]^T + b)   M=4096 N=2048 K=4640
    gemm_bt<0><<<dim3(32, 16), 256, 0, stream>>>(
        xb, DPAD, w1_pad, DPAD, DPAD / 32, hbuf, nullptr, N1, b11, b12);

    // stage B: muvar = h @ w2_pad^T (K-split, atomics)
    gemmB<<<dim3(BATCH / 16, 4), 64, 0, stream>>>(hbuf, w2_pad, muvar);

    // decode + symmetric-pair A2 (bf16, zero-padded)
    decode<<<BATCH / 16, 256, 0, stream>>>(muvar, eps, b21, b22, W3, b3, W4, b4, W5, b5,
                                           fcyw, fcyb, out_mu, out_lv, out_y, A2);

    // GEMM2: recon = sigmoid(A2sym @ w6sym^T + b6)  M=4096 N=4736(valid 4624) K=2368
    gemm_bt<1><<<dim3(32, N2PAD / 128), 256, 0, stream>>>(
        A2, K2PAD, w6s, K2PAD, K2PAD / 32, nullptr, out_recon, DDIM, b6, nullptr);
}

// Round 4
// 533.108 us; speedup vs baseline: 1.4405x; 1.1146x over previous
//
#include <hip/hip_runtime.h>
#include <hip/hip_bf16.h>
#include <cstdint>
#include <cstddef>

// ---------------- types / helpers ----------------
typedef __bf16 bf16x8 __attribute__((ext_vector_type(8)));
typedef __bf16 bf16x4 __attribute__((ext_vector_type(4)));
typedef float  floatx4 __attribute__((ext_vector_type(4)));

#define DEV __device__ __forceinline__

DEV __bf16 f2b(float x) { return (__bf16)x; }

// async global->LDS, 16B per lane. LDS dest semantics: wave-uniform base + lane*16.
DEV void async_ld16(const void* g, void* l) {
    __builtin_amdgcn_global_load_lds(
        (const __attribute__((address_space(1))) unsigned int*)g,
        (__attribute__((address_space(3))) unsigned int*)l,
        16, 0, 0);
}

// ---------------- constants ----------------
#define BATCH 4096
#define DDIM  4624          // 68*68
#define DPAD  4672          // GEMM1 K padded to mult of 64 (73*64)
#define LDIM  68
#define EDIM  1024
#define N1    2048          // fc11|fc12 fused
#define KB    2048          // stage-B K (h11|h12)
#define N2PAD 4736          // 37*128
#define NPAIR 2346          // 68*69/2 symmetric pairs
#define K2PAD 2368          // NPAIR padded: 37*64

// ======================================================================
// fp32 -> bf16 convert with zero padding. dst[rows_total][DPAD].
// ======================================================================
__global__ void cvt_pad(const float* __restrict__ src, int rows_valid, int K,
                        __bf16* __restrict__ dst, int rows_total) {
    const int gpr = DPAD / 4;   // 1168
    const long total = (long)rows_total * gpr;
    for (long g = blockIdx.x * (long)blockDim.x + threadIdx.x; g < total;
         g += gridDim.x * (long)blockDim.x) {
        int row = (int)(g / gpr);
        int c4  = (int)(g - (long)row * gpr) * 4;
        bf16x4 v;
        if (row < rows_valid && c4 < K) {
            floatx4 f = *(const floatx4*)(src + (size_t)row * K + c4);
            v[0] = f2b(f[0]); v[1] = f2b(f[1]); v[2] = f2b(f[2]); v[3] = f2b(f[3]);
        } else {
            v[0] = v[1] = v[2] = v[3] = (__bf16)0.0f;
        }
        *(bf16x4*)(dst + (size_t)row * DPAD + c4) = v;
    }
}

// w2_pad [144][2048] bf16: rows 0..67 = fc21 in cols 0..1023; rows 68..135 = fc22 in
// cols 1024..2047; everything else 0. (matches hbuf layout h11|h12)
__global__ void pad_w2(const float* __restrict__ w21, const float* __restrict__ w22,
                       __bf16* __restrict__ dst) {
    const int total = 144 * 512;
    for (int g = blockIdx.x * blockDim.x + threadIdx.x; g < total;
         g += gridDim.x * blockDim.x) {
        int row = g >> 9;
        int c4  = (g & 511) * 4;
        bf16x4 v;
        v[0] = v[1] = v[2] = v[3] = (__bf16)0.0f;
        if (row < 68 && c4 < 1024) {
            floatx4 f = *(const floatx4*)(w21 + (size_t)row * EDIM + c4);
            v[0] = f2b(f[0]); v[1] = f2b(f[1]); v[2] = f2b(f[2]); v[3] = f2b(f[3]);
        } else if (row >= 68 && row < 136 && c4 >= 1024) {
            floatx4 f = *(const floatx4*)(w22 + (size_t)(row - 68) * EDIM + (c4 - 1024));
            v[0] = f2b(f[0]); v[1] = f2b(f[1]); v[2] = f2b(f[2]); v[3] = f2b(f[3]);
        }
        *(bf16x4*)(dst + (size_t)row * KB + c4) = v;
    }
}

// ======================================================================
// pair table: p -> (i,j), i<=j, p = i*(137-i)/2 + (j-i). Built in LDS.
// ======================================================================
DEV void build_ptab(unsigned short* ptab, int t, int nthr) {
    for (int i = t; i < LDIM; i += nthr) {
        int p0 = i * (137 - i) / 2;
        for (int j = i; j < LDIM; ++j)
            ptab[p0 + (j - i)] = (unsigned short)((i << 8) | j);
    }
}

// ======================================================================
// w6sym: one block per output row o. dst[o][p] = w6[o][i,j] + w6[o][j,i] (i<j),
// w6[o][i,i] (i==j); zero pad for p>=NPAIR and o>=DDIM.
// ======================================================================
__global__ void w6sym_build(const float* __restrict__ w6, __bf16* __restrict__ dst) {
    __shared__ float row[DDIM];
    __shared__ unsigned short ptab[K2PAD];
    const int o = blockIdx.x;
    const int t = threadIdx.x;
    if (o < DDIM) {
        const float* src = w6 + (size_t)o * DDIM;
        for (int idx = t; idx < DDIM / 4; idx += 256)
            *(floatx4*)(row + idx * 4) = *(const floatx4*)(src + idx * 4);
    }
    build_ptab(ptab, t, 256);
    __syncthreads();
    for (int p4 = t; p4 < K2PAD / 4; p4 += 256) {
        bf16x4 v;
#pragma unroll
        for (int u = 0; u < 4; ++u) {
            int p = p4 * 4 + u;
            float val = 0.f;
            if (o < DDIM && p < NPAIR) {
                int ij = ptab[p];
                int i = ij >> 8, j = ij & 255;
                val = (i == j) ? row[i * LDIM + i] : (row[i * LDIM + j] + row[j * LDIM + i]);
            }
            v[u] = f2b(val);
        }
        *(bf16x4*)(dst + (size_t)o * K2PAD + p4 * 4) = v;
    }
}

// ======================================================================
// main MFMA GEMM: C[M,N] = epi(A[M,K] * W[N,K]^T + bias)
// 128x128 tile, BK=64 (halved barrier count vs BK=32), 4 waves, each 64x64
// via 4x4 frags of 16x16x32, 2 k-halves per staging.
// LDS chunk XOR-swizzle (chunk ^ (row&7)) on the GLOBAL-side address so the
// global_load_lds dest stays linear (m104/m108) while frag ds_read_b128s
// land 2-way-aliased across banks (free, m136) instead of 4-way+.
// EPI 0: relu(acc + (col<1024 ? b0[col] : b1[col-1024])) -> bf16 outb
// EPI 1: sigmoid(acc + b0[col]) -> fp32 outf, only col < DDIM
// ======================================================================
template <int EPI>
__launch_bounds__(256, 2)
__global__ void gemm_bt(const __bf16* __restrict__ A, int lda,
                        const __bf16* __restrict__ W, int ldb, int KT,
                        __bf16* __restrict__ outb, float* __restrict__ outf, int ldc,
                        const float* __restrict__ bias0, const float* __restrict__ bias1) {
    __shared__ __align__(16) __bf16 smA[128 * 64];   // 16 KB
    __shared__ __align__(16) __bf16 smB[128 * 64];   // 16 KB

    const int t  = threadIdx.x;
    const int l  = t & 63;
    const int w  = t >> 6;
    const int m0 = blockIdx.x * 128;
    const int n0 = blockIdx.y * 128;
    const int wm = (w & 1) * 64;
    const int wn = (w >> 1) * 64;

    // staging: thread t covers row t/8 (+32 per instr i=0..3), 16B chunk (t%8)
    // in LDS; fetches swizzled global chunk (t%8)^((t/8)&7). (i*32 ≡ 0 mod 8,
    // so the swizzle term is constant across i.)
    const int srow   = t >> 3;                       // 0..31
    const int schunk = (t & 7) ^ (srow & 7);
    const __bf16* pa = A + (size_t)(m0 + srow) * lda + schunk * 8;
    const __bf16* pb = W + (size_t)(n0 + srow) * ldb + schunk * 8;
    char* dA = (char*)smA + t * 16;
    char* dB = (char*)smB + t * 16;

    floatx4 acc[4][4];
#pragma unroll
    for (int mi = 0; mi < 4; ++mi)
#pragma unroll
        for (int ni = 0; ni < 4; ++ni) {
            floatx4 z = {0.f, 0.f, 0.f, 0.f};
            acc[mi][ni] = z;
        }

    for (int kt = 0; kt < KT; ++kt) {
#pragma unroll
        for (int i = 0; i < 4; ++i) {
            async_ld16(pa + (size_t)i * 32 * lda, dA + i * 4096);
            async_ld16(pb + (size_t)i * 32 * ldb, dB + i * 4096);
        }
        pa += 64; pb += 64;
        __syncthreads();

#pragma unroll
        for (int h = 0; h < 2; ++h) {
            bf16x8 af[4], bfr[4];
#pragma unroll
            for (int mi = 0; mi < 4; ++mi) {
                int r = wm + mi * 16 + (l & 15);
                int c = ((h << 2) | (l >> 4)) ^ (r & 7);
                af[mi] = *(const bf16x8*)((const char*)smA + r * 128 + c * 16);
            }
#pragma unroll
            for (int ni = 0; ni < 4; ++ni) {
                int r = wn + ni * 16 + (l & 15);
                int c = ((h << 2) | (l >> 4)) ^ (r & 7);
                bfr[ni] = *(const bf16x8*)((const char*)smB + r * 128 + c * 16);
            }
#pragma unroll
            for (int mi = 0; mi < 4; ++mi)
#pragma unroll
                for (int ni = 0; ni < 4; ++ni)
                    acc[mi][ni] = __builtin_amdgcn_mfma_f32_16x16x32_bf16(af[mi], bfr[ni],
                                                                         acc[mi][ni], 0, 0, 0);
        }
        __syncthreads();
    }

    // epilogue: C/D layout col = lane&15, row = (lane>>4)*4 + reg  [m89/m91]
    const int colbase = n0 + wn + (l & 15);
    const int rowbase = m0 + wm + (l >> 4) * 4;
#pragma unroll
    for (int ni = 0; ni < 4; ++ni) {
        int col = colbase + ni * 16;
        if (EPI == 1 && col >= DDIM) continue;
        float bias = (EPI == 0)
                         ? ((col < 1024) ? bias0[col] : bias1[col - 1024])
                         : bias0[col];
#pragma unroll
        for (int mi = 0; mi < 4; ++mi) {
            int row = rowbase + mi * 16;
#pragma unroll
            for (int r = 0; r < 4; ++r) {
                float v = acc[mi][ni][r] + bias;
                if (EPI == 0) {
                    v = v > 0.f ? v : 0.f;
                    outb[(size_t)(row + r) * ldc + col] = f2b(v);
                } else {
                    v = 1.f / (1.f + __expf(-v));
                    outf[(size_t)(row + r) * ldc + col] = v;
                }
            }
        }
    }
}

// ======================================================================
// stage B: muvar[4096][136] += h[4096][2048] * w2_pad[144][2048]^T (K-split x4, atomics)
// ======================================================================
__launch_bounds__(64, 4)
__global__ void gemmB(const __bf16* __restrict__ h, const __bf16* __restrict__ w2,
                      float* __restrict__ muvar) {
    const int l    = threadIdx.x;
    const int m0   = blockIdx.x * 16;
    const int k0   = blockIdx.y * 512;
    const int row  = l & 15;
    const int quad = l >> 4;

    floatx4 acc[9];
#pragma unroll
    for (int ni = 0; ni < 9; ++ni) {
        floatx4 z = {0.f, 0.f, 0.f, 0.f};
        acc[ni] = z;
    }

    const __bf16* ap = h + (size_t)(m0 + row) * KB + k0 + quad * 8;
    for (int kt = 0; kt < 16; ++kt) {
        bf16x8 a = *(const bf16x8*)ap;
        ap += 32;
#pragma unroll
        for (int ni = 0; ni < 9; ++ni) {
            const __bf16* bp = w2 + (size_t)(ni * 16 + row) * KB + k0 + kt * 32 + quad * 8;
            bf16x8 b = *(const bf16x8*)bp;
            acc[ni] = __builtin_amdgcn_mfma_f32_16x16x32_bf16(a, b, acc[ni], 0, 0, 0);
        }
    }
#pragma unroll
    for (int ni = 0; ni < 9; ++ni) {
        int col = ni * 16 + row;
        if (col < 136) {
#pragma unroll
            for (int r = 0; r < 4; ++r) {
                int orow = m0 + quad * 4 + r;
                atomicAdd(&muvar[(size_t)orow * 136 + col], acc[ni][r]);
            }
        }
    }
}

// ======================================================================
// decode (fp32): mu/logvar(+bias) -> z -> h3_0 -> h4_0 -> h51 -> symmetric-pair A2
// also writes mu, logvar, y. Branches 1..4 dead (recon uses h51 only).
// ======================================================================
__global__ void decode(const float* __restrict__ muvar, const float* __restrict__ eps,
                       const float* __restrict__ b21, const float* __restrict__ b22,
                       const float* __restrict__ W3, const float* __restrict__ b3,
                       const float* __restrict__ W4, const float* __restrict__ b4,
                       const float* __restrict__ W5, const float* __restrict__ b5,
                       const float* __restrict__ fcyw, const float* __restrict__ fcyb,
                       float* __restrict__ out_mu, float* __restrict__ out_lv,
                       float* __restrict__ out_y, __bf16* __restrict__ A2) {
    __shared__ float w3s[DDIM], w4s[DDIM], w5s[DDIM];
    __shared__ float b3s[LDIM], b4s[LDIM], b5s[LDIM], fys[LDIM];
    __shared__ float zb[16][LDIM], h3b[16][LDIM], h51b[16][LDIM];
    __shared__ unsigned short ptab[K2PAD];

    const int t  = threadIdx.x;
    const int r0 = blockIdx.x * 16;

    for (int i = t; i < DDIM; i += 256) {  // branch 0 = first 68*68 of each tensor
        w3s[i] = W3[i];
        w4s[i] = W4[i];
        w5s[i] = W5[i];
    }
    if (t < LDIM) {
        b3s[t] = b3[t];
        b4s[t] = b4[t];
        b5s[t] = b5[t];
        fys[t] = fcyw[t];
    }
    build_ptab(ptab, t, 256);
    __syncthreads();

    for (int idx = t; idx < 16 * LDIM; idx += 256) {
        int r = idx / LDIM, o = idx - r * LDIM;
        int row = r0 + r;
        float mu = muvar[(size_t)row * 136 + o] + b21[o];
        float lv = muvar[(size_t)row * 136 + 68 + o] + b22[o];
        float z  = mu + eps[(size_t)row * LDIM + o] * __expf(0.5f * lv);
        zb[r][o] = z;
        out_mu[(size_t)row * LDIM + o] = mu;
        out_lv[(size_t)row * LDIM + o] = lv;
    }
    if (t < 16) {
        int row = r0 + t;
        float s = fcyb[0];
        for (int o = 0; o < LDIM; ++o)
            s += (muvar[(size_t)row * 136 + o] + b21[o]) * fys[o];
        out_y[row] = s;
    }
    __syncthreads();

    // h3_0 = z @ W3_0^T + b3_0   (branch 0: NO sigmoid)
    for (int idx = t; idx < 16 * LDIM; idx += 256) {
        int r = idx / LDIM, o = idx - r * LDIM;
        float s = b3s[o];
        for (int d = 0; d < LDIM; ++d) s += zb[r][d] * w3s[o * LDIM + d];
        h3b[r][o] = s;
    }
    __syncthreads();

    // h4_0 = sigmoid(h3_0 @ W4_0^T + b4_0)  -> reuse zb
    for (int idx = t; idx < 16 * LDIM; idx += 256) {
        int r = idx / LDIM, o = idx - r * LDIM;
        float s = b4s[o];
        for (int d = 0; d < LDIM; ++d) s += h3b[r][d] * w4s[o * LDIM + d];
        zb[r][o] = 1.f / (1.f + __expf(-s));
    }
    __syncthreads();

    // h51 = h4_0 @ W5_0^T + b5_0
    for (int idx = t; idx < 16 * LDIM; idx += 256) {
        int r = idx / LDIM, o = idx - r * LDIM;
        float s = b5s[o];
        for (int d = 0; d < LDIM; ++d) s += zb[r][d] * w5s[o * LDIM + d];
        h51b[r][o] = s;
    }
    __syncthreads();

    // symmetric-pair "outer product": A2[row][p] = h51[i]*h51[j] (factor 2 folded into w6sym)
    for (int idx = t; idx < 16 * (K2PAD / 4); idx += 256) {
        int r  = idx / (K2PAD / 4);
        int p4 = (idx - r * (K2PAD / 4)) * 4;
        int row = r0 + r;
        bf16x4 v;
#pragma unroll
        for (int u = 0; u < 4; ++u) {
            int p = p4 + u;
            float val = 0.f;
            if (p < NPAIR) {
                int ij = ptab[p];
                val = h51b[r][ij >> 8] * h51b[r][ij & 255];
            }
            v[u] = f2b(val);
        }
        *(bf16x4*)(A2 + (size_t)row * K2PAD + p4) = v;
    }
}

// ======================================================================
extern "C" void kernel_launch(void* const* d_in, const int* in_sizes, int n_in,
                              void* d_out, int out_size, void* d_ws, size_t ws_size,
                              hipStream_t stream) {
    const float* x    = (const float*)d_in[0];
    const float* eps  = (const float*)d_in[1];
    const float* w11  = (const float*)d_in[2];
    const float* b11  = (const float*)d_in[3];
    const float* w12  = (const float*)d_in[4];
    const float* b12  = (const float*)d_in[5];
    const float* w21  = (const float*)d_in[6];
    const float* b21  = (const float*)d_in[7];
    const float* w22  = (const float*)d_in[8];
    const float* b22  = (const float*)d_in[9];
    const float* W3   = (const float*)d_in[10];
    const float* b3   = (const float*)d_in[11];
    const float* W4   = (const float*)d_in[12];
    const float* b4   = (const float*)d_in[13];
    const float* W5   = (const float*)d_in[14];
    const float* b5   = (const float*)d_in[15];
    const float* w6   = (const float*)d_in[16];
    const float* b6   = (const float*)d_in[17];
    const float* fcyw = (const float*)d_in[18];
    const float* fcyb = (const float*)d_in[19];

    float* out       = (float*)d_out;
    float* out_recon = out;
    float* out_mu    = out + (size_t)BATCH * DDIM;
    float* out_lv    = out_mu + (size_t)BATCH * LDIM;
    float* out_y     = out_lv + (size_t)BATCH * LDIM;

    // ws layout (bytes, 256B-aligned)
    char* ws = (char*)d_ws;
    size_t off = 0;
    __bf16* xb     = (__bf16*)(ws + off); off += (size_t)BATCH * DPAD * 2;   // 38.3 MB
    __bf16* w1_pad = (__bf16*)(ws + off); off += (size_t)N1 * DPAD * 2;      // 19.1 MB
    __bf16* w6s    = (__bf16*)(ws + off); off += (size_t)N2PAD * K2PAD * 2;  // 22.4 MB
    __bf16* hbuf   = (__bf16*)(ws + off); off += (size_t)BATCH * KB * 2;     // 16.8 MB
    __bf16* w2_pad = (__bf16*)(ws + off); off += (size_t)144 * KB * 2;       //  0.6 MB
    float*  muvar  = (float*) (ws + off); off += (size_t)BATCH * 136 * 4;    //  2.2 MB
    __bf16* A2     = (__bf16*)(ws + off);                                    // 19.4 MB
    // total ~119 MB

    hipMemsetAsync(muvar, 0, (size_t)BATCH * 136 * 4, stream);

    // fp32 -> zero-padded bf16 staging buffers
    cvt_pad<<<2048, 256, 0, stream>>>(x, BATCH, DDIM, xb, BATCH);
    cvt_pad<<<512, 256, 0, stream>>>(w11, 1024, DDIM, w1_pad, 1024);
    cvt_pad<<<512, 256, 0, stream>>>(w12, 1024, DDIM, w1_pad + (size_t)1024 * DPAD, 1024);
    w6sym_build<<<N2PAD, 256, 0, stream>>>(w6, w6s);
    pad_w2<<<72, 256, 0, stream>>>(w21, w22, w2_pad);

    // GEMM1: h = relu(x @ [fc11|fc12]^T + b)   M=4096 N=2048 K=4672
    gemm_bt<0><<<dim3(32, 16), 256, 0, stream>>>(
        xb, DPAD, w1_pad, DPAD, DPAD / 64, hbuf, nullptr, N1, b11, b12);

    // stage B: muvar = h @ w2_pad^T (K-split, atomics)
    gemmB<<<dim3(BATCH / 16, 4), 64, 0, stream>>>(hbuf, w2_pad, muvar);

    // decode + symmetric-pair A2 (bf16, zero-padded)
    decode<<<BATCH / 16, 256, 0, stream>>>(muvar, eps, b21, b22, W3, b3, W4, b4, W5, b5,
                                           fcyw, fcyb, out_mu, out_lv, out_y, A2);

    // GEMM2: recon = sigmoid(A2sym @ w6sym^T + b6)  M=4096 N=4736(valid 4624) K=2368
    gemm_bt<1><<<dim3(32, N2PAD / 128), 256, 0, stream>>>(
        A2, K2PAD, w6s, K2PAD, K2PAD / 64, nullptr, out_recon, DDIM, b6, nullptr);
}